// Round 1
// baseline (2122.873 us; speedup 1.0000x reference)
//
#include <hip/hip_runtime.h>
#include <hip/hip_bf16.h>
#include <stdint.h>

typedef __attribute__((ext_vector_type(4))) float f32x4;
typedef __attribute__((ext_vector_type(8))) short bf16x8;
typedef __attribute__((ext_vector_type(4))) short short4_t;

#define NN 8192
#define DD 256

// Split f32 v into hi/lo bf16 (truncation): v = hi + lo + O(2^-17 |v|)
__device__ __forceinline__ void split2(float v, short& h, short& l) {
    uint32_t b = __builtin_bit_cast(uint32_t, v);
    h = (short)(b >> 16);
    float hf = __builtin_bit_cast(float, b & 0xffff0000u);
    float lof = v - hf;                       // exact
    l = (short)(__builtin_bit_cast(uint32_t, lof) >> 16);
}

#define MFMA(A, B, C) __builtin_amdgcn_mfma_f32_16x16x32_bf16((A), (B), (C), 0, 0, 0)

// ---------------------------------------------------------------------------
// prep_x: x[8192][256] f32 -> xT_hi/xT_lo [256][8192] bf16 (transpose + split)
// ---------------------------------------------------------------------------
__global__ void prep_x_kernel(const float* __restrict__ x,
                              short* __restrict__ xTh, short* __restrict__ xTl)
{
    __shared__ float tile[32][33];
    const int tx = threadIdx.x;            // 0..31
    const int ty = threadIdx.y;            // 0..7
    const int k0 = blockIdx.x * 32;
    const int d0 = blockIdx.y * 32;
#pragma unroll
    for (int i = 0; i < 32; i += 8)
        tile[ty + i][tx] = x[(size_t)(k0 + ty + i) * DD + d0 + tx];
    __syncthreads();
#pragma unroll
    for (int i = 0; i < 32; i += 8) {
        float v = tile[tx][ty + i];        // = x[k0+tx][d0+ty+i]
        short h, l; split2(v, h, l);
        const size_t o = (size_t)(d0 + ty + i) * NN + (k0 + tx);
        xTh[o] = h; xTl[o] = l;
    }
}

// ---------------------------------------------------------------------------
// prep_w: W[256][256] f32 -> Whi/Wlo bf16 (no transpose needed; B-frag reads
// W rows: B[k=d][n=j] with lane holding 8 consecutive d of row j)
// ---------------------------------------------------------------------------
__global__ void prep_w_kernel(const float* __restrict__ W,
                              short* __restrict__ Wh, short* __restrict__ Wl)
{
    const int i = blockIdx.x * 256 + threadIdx.x;   // grid 256 -> 65536 elems
    short h, l; split2(W[i], h, l);
    Wh[i] = h; Wl[i] = l;
}

// ---------------------------------------------------------------------------
// gemm1: P_partial[chunk] = (sum_s theta_s*T_s * a)[rows, kchunk] @ x[kchunk,:]
// Wave tile: 32 rows x 256 cols. A-frags computed in-register from T/a.
// B-frags loaded from pre-split xT (L2-resident). No LDS, no barriers.
// ---------------------------------------------------------------------------
__global__ __launch_bounds__(256, 2)
void gemm1_kernel(const float* __restrict__ theta,
                  const float* __restrict__ T,
                  const float* __restrict__ Amat,
                  const short* __restrict__ xTh,
                  const short* __restrict__ xTl,
                  float* __restrict__ Pp,
                  int nchunk)
{
    const int lane  = threadIdx.x & 63;
    const int wv    = threadIdx.x >> 6;
    const int chunk = blockIdx.x % nchunk;       // XCD-aligned K-chunk
    const int rowg  = blockIdx.x / nchunk;
    const int kspan = NN / nchunk;
    const int kbeg  = chunk * kspan;
    const int row0  = rowg * 128 + wv * 32;
    const int lr    = lane & 15;                 // A row / B col within frag
    const int lk    = (lane >> 4) << 3;          // k sub-offset within 32

    const float th0 = theta[0], th1 = theta[1], th2 = theta[2], th3 = theta[3];
    const size_t TS = (size_t)NN * NN;

    f32x4 acc[2][16];
#pragma unroll
    for (int m = 0; m < 2; ++m)
#pragma unroll
        for (int n = 0; n < 16; ++n)
            acc[m][n] = (f32x4)0.f;

    for (int it = 0; it < (kspan >> 5); ++it) {
        const int k = kbeg + (it << 5) + lk;
        bf16x8 Ah[2], Al[2];
#pragma unroll
        for (int m = 0; m < 2; ++m) {
            const size_t base = (size_t)(row0 + m * 16 + lr) * NN + k;
            f32x4 t0a = __builtin_nontemporal_load((const f32x4*)(T + base));
            f32x4 t0b = __builtin_nontemporal_load((const f32x4*)(T + base + 4));
            f32x4 t1a = __builtin_nontemporal_load((const f32x4*)(T + TS + base));
            f32x4 t1b = __builtin_nontemporal_load((const f32x4*)(T + TS + base + 4));
            f32x4 t2a = __builtin_nontemporal_load((const f32x4*)(T + 2 * TS + base));
            f32x4 t2b = __builtin_nontemporal_load((const f32x4*)(T + 2 * TS + base + 4));
            f32x4 t3a = __builtin_nontemporal_load((const f32x4*)(T + 3 * TS + base));
            f32x4 t3b = __builtin_nontemporal_load((const f32x4*)(T + 3 * TS + base + 4));
            f32x4 aa  = __builtin_nontemporal_load((const f32x4*)(Amat + base));
            f32x4 ab  = __builtin_nontemporal_load((const f32x4*)(Amat + base + 4));
            f32x4 w0 = (t0a * th0 + t1a * th1 + t2a * th2 + t3a * th3) * aa;
            f32x4 w1 = (t0b * th0 + t1b * th1 + t2b * th2 + t3b * th3) * ab;
#pragma unroll
            for (int j = 0; j < 4; ++j) {
                short h, l;
                split2(w0[j], h, l); Ah[m][j] = h;     Al[m][j] = l;
                split2(w1[j], h, l); Ah[m][4 + j] = h; Al[m][4 + j] = l;
            }
        }
        const short* bh = xTh + (size_t)lr * NN + k;
        const short* bl = xTl + (size_t)lr * NN + k;
#pragma unroll
        for (int nf = 0; nf < 16; ++nf) {
            bf16x8 Bh = *(const bf16x8*)(bh + (size_t)nf * 16 * NN);
            bf16x8 Bl = *(const bf16x8*)(bl + (size_t)nf * 16 * NN);
#pragma unroll
            for (int m = 0; m < 2; ++m) {
                acc[m][nf] = MFMA(Ah[m], Bh, acc[m][nf]);
                acc[m][nf] = MFMA(Ah[m], Bl, acc[m][nf]);
                acc[m][nf] = MFMA(Al[m], Bh, acc[m][nf]);
            }
        }
    }

    // C/D layout: col = lane&15, row = (lane>>4)*4 + r   [guide m89]
    const int sr = (lane >> 4) << 2;
    const int sc = lane & 15;
#pragma unroll
    for (int m = 0; m < 2; ++m)
#pragma unroll
        for (int nf = 0; nf < 16; ++nf)
#pragma unroll
            for (int r = 0; r < 4; ++r) {
                const int row = row0 + m * 16 + sr + r;
                const int col = nf * 16 + sc;
                Pp[((size_t)chunk * NN + row) * DD + col] = acc[m][nf][r];
            }
}

// ---------------------------------------------------------------------------
// reduce partials + PReLU + split to bf16 hi/lo
// ---------------------------------------------------------------------------
__global__ __launch_bounds__(256)
void reduce_prelu_kernel(const float* __restrict__ Pp,
                         const float* __restrict__ alpha,
                         short* __restrict__ P2h, short* __restrict__ P2l,
                         int nchunk)
{
    const size_t idx = ((size_t)blockIdx.x * 256 + threadIdx.x) * 4;
    f32x4 s = (f32x4)0.f;
    for (int c = 0; c < nchunk; ++c)
        s += *(const f32x4*)(Pp + (size_t)c * NN * DD + idx);
    const int d = (int)(idx & (DD - 1));
    f32x4 al = *(const f32x4*)(alpha + d);
    short4_t hh, ll;
#pragma unroll
    for (int j = 0; j < 4; ++j) {
        float v = s[j];
        v = (v >= 0.f) ? v : al[j] * v;
        short h, l; split2(v, h, l);
        hh[j] = h; ll[j] = l;
    }
    *(short4_t*)(P2h + idx) = hh;
    *(short4_t*)(P2l + idx) = ll;
}

// ---------------------------------------------------------------------------
// gemm2: out = P2 @ W^T + b.  M=8192, K=256, N=256. Wave = 16 rows x 256 cols.
// ---------------------------------------------------------------------------
__global__ __launch_bounds__(256, 4)
void gemm2_kernel(const short* __restrict__ P2h, const short* __restrict__ P2l,
                  const short* __restrict__ Wh, const short* __restrict__ Wl,
                  const float* __restrict__ bias, float* __restrict__ out)
{
    const int lane = threadIdx.x & 63;
    const int wv   = threadIdx.x >> 6;
    const int row0 = (blockIdx.x * 4 + wv) * 16;
    const int lr   = lane & 15;
    const int lk   = (lane >> 4) << 3;

    f32x4 acc[16];
#pragma unroll
    for (int n = 0; n < 16; ++n) acc[n] = (f32x4)0.f;

#pragma unroll
    for (int it = 0; it < 8; ++it) {
        const int d = (it << 5) + lk;
        bf16x8 Ah = *(const bf16x8*)(P2h + (size_t)(row0 + lr) * DD + d);
        bf16x8 Al = *(const bf16x8*)(P2l + (size_t)(row0 + lr) * DD + d);
#pragma unroll
        for (int nf = 0; nf < 16; ++nf) {
            const size_t wb = (size_t)(nf * 16 + lr) * DD + d;  // W row j = col
            bf16x8 Bh = *(const bf16x8*)(Wh + wb);
            bf16x8 Bl = *(const bf16x8*)(Wl + wb);
            acc[nf] = MFMA(Ah, Bh, acc[nf]);
            acc[nf] = MFMA(Ah, Bl, acc[nf]);
            acc[nf] = MFMA(Al, Bh, acc[nf]);
        }
    }
    const int sr = (lane >> 4) << 2;
#pragma unroll
    for (int nf = 0; nf < 16; ++nf) {
        const int col = nf * 16 + (lane & 15);
        const float bb = bias[col];
#pragma unroll
        for (int r = 0; r < 4; ++r)
            out[(size_t)(row0 + sr + r) * DD + col] = acc[nf][r] + bb;
    }
}

// ---------------------------------------------------------------------------
extern "C" void kernel_launch(void* const* d_in, const int* in_sizes, int n_in,
                              void* d_out, int out_size, void* d_ws, size_t ws_size,
                              hipStream_t stream)
{
    const float* theta = (const float*)d_in[0];
    const float* T     = (const float*)d_in[1];
    const float* x     = (const float*)d_in[2];
    const float* a     = (const float*)d_in[3];
    const float* Wfc   = (const float*)d_in[4];
    const float* bfc   = (const float*)d_in[5];
    const float* alpha = (const float*)d_in[6];
    float* out = (float*)d_out;

    char* ws = (char*)d_ws;
    // ws layout (bytes):
    short* xTh = (short*)(ws + 0);          // 4 MB
    short* xTl = (short*)(ws + 4194304);    // 4 MB
    short* Wh  = (short*)(ws + 8388608);    // 128 KB
    short* Wl  = (short*)(ws + 8519680);    // 128 KB
    short* P2h = (short*)(ws + 8650752);    // 4 MB
    short* P2l = (short*)(ws + 12845056);   // 4 MB
    float* Pp  = (float*)(ws + 17039360);   // nchunk * 8 MB

    int nchunk = 1;
    for (int c = 8; c >= 1; c >>= 1)
        if (17039360ull + (size_t)c * 8388608ull <= ws_size) { nchunk = c; break; }

    prep_x_kernel<<<dim3(NN / 32, DD / 32), dim3(32, 8), 0, stream>>>(x, xTh, xTl);
    prep_w_kernel<<<256, 256, 0, stream>>>(Wfc, Wh, Wl);
    gemm1_kernel<<<64 * nchunk, 256, 0, stream>>>(theta, T, a, xTh, xTl, Pp, nchunk);
    reduce_prelu_kernel<<<2048, 256, 0, stream>>>(Pp, alpha, P2h, P2l, nchunk);
    gemm2_kernel<<<128, 256, 0, stream>>>(P2h, P2l, Wh, Wl, bfc, out);
}